// Round 1
// baseline (4346.496 us; speedup 1.0000x reference)
//
#include <hip/hip_runtime.h>
#include <math.h>

#define N_NODES 2048
#define HID 64
#define BATCH 8
#define SEQ 32
#define CAP 128   // ELL slots per row (expected nnz/row ~33, binomial tail << CAP)

// ---------------- Kernel 0: build ELL sparse format of L (deterministic) ----
// One wave per row; ballot-based compaction preserving column order.
__global__ __launch_bounds__(256) void k_build_ell(
    const float* __restrict__ L, float* __restrict__ ell_val,
    int* __restrict__ ell_col, int* __restrict__ ell_cnt) {
  int wave = (blockIdx.x * blockDim.x + threadIdx.x) >> 6;
  int lane = threadIdx.x & 63;
  if (wave >= N_NODES) return;
  const float* row = L + (size_t)wave * N_NODES;
  int base = 0;
  for (int c = 0; c < N_NODES / 64; ++c) {
    int col = c * 64 + lane;
    float v = row[col];
    bool nz = (v != 0.0f);
    unsigned long long mask = __ballot(nz);
    int before = __popcll(mask & ((1ull << lane) - 1ull));
    if (nz) {
      int slot = base + before;
      if (slot < CAP) {
        ell_col[wave * CAP + slot] = col;
        ell_val[wave * CAP + slot] = v;
      }
    }
    base += __popcll(mask);
  }
  if (lane == 0) ell_cnt[wave] = (base < CAP) ? base : CAP;
}

// ---------------- Kernel Lx: Lx[t][b][m] = sum_n L[m,n] * x[b,t,n] ----------
// One wave per output element; lane-parallel over nnz, shuffle reduce.
__global__ __launch_bounds__(256) void k_lx(
    const float* __restrict__ x, const float* __restrict__ ell_val,
    const int* __restrict__ ell_col, const int* __restrict__ ell_cnt,
    float* __restrict__ Lx) {
  int wid = (blockIdx.x * blockDim.x + threadIdx.x) >> 6;
  int lane = threadIdx.x & 63;
  if (wid >= SEQ * BATCH * N_NODES) return;
  int m = wid & (N_NODES - 1);
  int tb = wid >> 11;            // t*BATCH + b
  int b = tb & (BATCH - 1);
  int t = tb >> 3;
  const float* xr = x + ((size_t)b * SEQ + t) * N_NODES;
  int cnt = ell_cnt[m];
  float acc = 0.f;
  for (int k = lane; k < cnt; k += 64)
    acc += ell_val[m * CAP + k] * xr[ell_col[m * CAP + k]];
  for (int off = 32; off; off >>= 1) acc += __shfl_down(acc, off);
  if (lane == 0) Lx[wid] = acc;
}

// ---------------- Kernel 1: gates = sigmoid( [Lx | L@state] @ Wg^T + bg ) ---
// One wave per (b, m) output row. lane = feature h for the SpMM, then
// lane = output o (2 reps for 128 outputs).
__global__ __launch_bounds__(256) void k_gates(
    const float* __restrict__ state, const float* __restrict__ Lx,
    const float* __restrict__ ell_val, const int* __restrict__ ell_col,
    const int* __restrict__ ell_cnt, const float* __restrict__ Wg,
    const float* __restrict__ bg, float* __restrict__ gates, int t) {
  __shared__ float sW[128 * 65];
  __shared__ float sb[128];
  __shared__ float sdiff[4][64];
  for (int i = threadIdx.x; i < 128 * 65; i += 256) sW[i] = Wg[i];
  if (threadIdx.x < 128) sb[threadIdx.x] = bg[threadIdx.x];
  __syncthreads();
  int wv = threadIdx.x >> 6, lane = threadIdx.x & 63;
  int row = blockIdx.x * 4 + wv;          // b*N + m
  int b = row >> 11, m = row & (N_NODES - 1);
  const float* st = state + (size_t)b * (N_NODES * HID);
  int cnt = ell_cnt[m];
  float acc = 0.f;
  for (int k = 0; k < cnt; ++k) {
    int col = ell_col[m * CAP + k];       // wave-uniform
    float v = ell_val[m * CAP + k];       // wave-uniform
    acc += v * st[col * HID + lane];      // coalesced 256B gather
  }
  sdiff[wv][lane] = acc;
  __syncthreads();
  float Lxv = Lx[((size_t)t * BATCH + b) * N_NODES + m];
  float* gout = gates + (size_t)b * (N_NODES * 128) + m * 128;
  #pragma unroll
  for (int rep = 0; rep < 2; ++rep) {
    int o = lane + rep * 64;
    float s = sb[o] + Lxv * sW[o * 65];
    #pragma unroll
    for (int h = 0; h < 64; ++h) s += sdiff[wv][h] * sW[o * 65 + 1 + h];
    gout[o] = 1.f / (1.f + __expf(-s));
  }
}

// ---------------- Kernel 2: cand + GRU update, writes out[t] & next state ---
// Flat-split semantics: r[b,j] = gates[b][j], u[b,j] = gates[b][N*H + j].
__global__ __launch_bounds__(256) void k_cand(
    const float* __restrict__ state, const float* __restrict__ Lx,
    const float* __restrict__ ell_val, const int* __restrict__ ell_col,
    const int* __restrict__ ell_cnt, const float* __restrict__ Wc,
    const float* __restrict__ bc, const float* __restrict__ gates,
    float* __restrict__ state_next, float* __restrict__ out, int t) {
  __shared__ float sW[64 * 65];
  __shared__ float sb[64];
  __shared__ float sdiff[4][64];
  for (int i = threadIdx.x; i < 64 * 65; i += 256) sW[i] = Wc[i];
  if (threadIdx.x < 64) sb[threadIdx.x] = bc[threadIdx.x];
  __syncthreads();
  int wv = threadIdx.x >> 6, lane = threadIdx.x & 63;
  int row = blockIdx.x * 4 + wv;
  int b = row >> 11, m = row & (N_NODES - 1);
  const float* st = state + (size_t)b * (N_NODES * HID);
  const float* gb = gates + (size_t)b * (N_NODES * 128);
  int cnt = ell_cnt[m];
  float acc = 0.f;
  for (int k = 0; k < cnt; ++k) {
    int col = ell_col[m * CAP + k];
    float v = ell_val[m * CAP + k];
    int j = col * HID + lane;
    acc += v * (gb[j] * st[j]);           // rs = r * state, flat index j
  }
  sdiff[wv][lane] = acc;
  __syncthreads();
  float Lxv = Lx[((size_t)t * BATCH + b) * N_NODES + m];
  int o = lane;
  float s = sb[o] + Lxv * sW[o * 65];
  #pragma unroll
  for (int h = 0; h < 64; ++h) s += sdiff[wv][h] * sW[o * 65 + 1 + h];
  float cand = tanhf(s);
  int j = m * HID + o;
  float u = gb[N_NODES * HID + j];
  float hp = st[j];
  float nh = u * hp + (1.f - u) * cand;
  state_next[(size_t)b * (N_NODES * HID) + j] = nh;
  out[((size_t)t * BATCH + b) * (N_NODES * HID) + j] = nh;
}

extern "C" void kernel_launch(void* const* d_in, const int* in_sizes, int n_in,
                              void* d_out, int out_size, void* d_ws, size_t ws_size,
                              hipStream_t stream) {
  const float* x  = (const float*)d_in[0];
  const float* L  = (const float*)d_in[1];
  const float* Wg = (const float*)d_in[2];
  const float* bg = (const float*)d_in[3];
  const float* Wc = (const float*)d_in[4];
  const float* bc = (const float*)d_in[5];
  float* out = (float*)d_out;
  char* ws = (char*)d_ws;

  float* ell_val = (float*)ws;                                   // 2048*CAP
  int*   ell_col = (int*)(ws + (size_t)N_NODES * CAP * 4);       // 2048*CAP
  int*   ell_cnt = (int*)(ws + (size_t)2 * N_NODES * CAP * 4);   // 2048
  float* Lx    = (float*)(ws + ((size_t)2 * N_NODES * CAP + N_NODES) * 4);
  float* gates = Lx + (size_t)SEQ * BATCH * N_NODES;             // B*N*128
  float* stA   = gates + (size_t)BATCH * N_NODES * 128;          // B*N*64
  float* stB   = stA + (size_t)BATCH * N_NODES * HID;            // B*N*64

  k_build_ell<<<N_NODES / 4, 256, 0, stream>>>(L, ell_val, ell_col, ell_cnt);
  hipMemsetAsync(stA, 0, (size_t)BATCH * N_NODES * HID * sizeof(float), stream);
  k_lx<<<SEQ * BATCH * N_NODES / 4, 256, 0, stream>>>(x, ell_val, ell_col, ell_cnt, Lx);

  float* cur = stA;
  float* nxt = stB;
  for (int t = 0; t < SEQ; ++t) {
    k_gates<<<BATCH * N_NODES / 4, 256, 0, stream>>>(cur, Lx, ell_val, ell_col,
                                                     ell_cnt, Wg, bg, gates, t);
    k_cand<<<BATCH * N_NODES / 4, 256, 0, stream>>>(cur, Lx, ell_val, ell_col,
                                                    ell_cnt, Wc, bc, gates, nxt,
                                                    out, t);
    float* tmp = cur; cur = nxt; nxt = tmp;
  }
}

// Round 2
// 3767.571 us; speedup vs baseline: 1.1537x; 1.1537x over previous
//
#include <hip/hip_runtime.h>
#include <math.h>

#define N_NODES 2048
#define HID 64
#define BATCH 8
#define SEQ 32
#define CAP 128          // ELL slots per row (nnz/row ~33)
#define TB (BATCH*SEQ)   // 256

// ---------------- Kernel 0: build ELL sparse format of L (deterministic) ----
__global__ __launch_bounds__(256) void k_build_ell(
    const float* __restrict__ L, float* __restrict__ ell_val,
    int* __restrict__ ell_col, int* __restrict__ ell_cnt) {
  int wave = (blockIdx.x * blockDim.x + threadIdx.x) >> 6;
  int lane = threadIdx.x & 63;
  if (wave >= N_NODES) return;
  const float* row = L + (size_t)wave * N_NODES;
  int base = 0;
  for (int c = 0; c < N_NODES / 64; ++c) {
    int col = c * 64 + lane;
    float v = row[col];
    bool nz = (v != 0.0f);
    unsigned long long mask = __ballot(nz);
    int before = __popcll(mask & ((1ull << lane) - 1ull));
    if (nz) {
      int slot = base + before;
      if (slot < CAP) {
        ell_col[wave * CAP + slot] = col;
        ell_val[wave * CAP + slot] = v;
      }
    }
    base += __popcll(mask);
  }
  if (lane == 0) ell_cnt[wave] = (base < CAP) ? base : CAP;
}

// ---------------- Transpose x[b][t][n] -> xT[n][tb],  tb = t*8 + b ----------
__global__ __launch_bounds__(256) void k_xt(const float* __restrict__ x,
                                            float* __restrict__ xT) {
  __shared__ float s[32][65];
  int n0  = (blockIdx.x & 63) * 32;   // 64 n-tiles
  int tb0 = (blockIdx.x >> 6) * 64;   // 4 tb-tiles
  for (int idx = threadIdx.x; idx < 32 * 64; idx += 256) {
    int ln = idx & 31, ltb = idx >> 5;
    int tb = tb0 + ltb; int b = tb & 7, t = tb >> 3;
    s[ln][ltb] = x[((size_t)b * SEQ + t) * N_NODES + n0 + ln];
  }
  __syncthreads();
  for (int idx = threadIdx.x; idx < 32 * 64; idx += 256) {
    int ln = idx >> 6, ltb = idx & 63;
    xT[(size_t)(n0 + ln) * TB + tb0 + ltb] = s[ln][ltb];
  }
}

// ---------------- LxT[m][tb] = sum_n L[m,n] * xT[n][tb] ---------------------
// One wave per row m; lane covers 4 tb values (64*4 = 256 = TB).
__global__ __launch_bounds__(512) void k_spmm_x(
    const float* __restrict__ xT, const float* __restrict__ ell_val,
    const int* __restrict__ ell_col, const int* __restrict__ ell_cnt,
    float* __restrict__ LxT) {
  int m = (blockIdx.x * blockDim.x + threadIdx.x) >> 6;
  int lane = threadIdx.x & 63;
  if (m >= N_NODES) return;
  int cnt = ell_cnt[m];
  float4 acc = {0.f, 0.f, 0.f, 0.f};
  for (int k = 0; k < cnt; ++k) {
    int col = ell_col[m * CAP + k];
    float v = ell_val[m * CAP + k];
    const float4 xv = *(const float4*)&xT[(size_t)col * TB + lane * 4];
    acc.x += v * xv.x; acc.y += v * xv.y; acc.z += v * xv.z; acc.w += v * xv.w;
  }
  *(float4*)&LxT[(size_t)m * TB + lane * 4] = acc;
}

// ---------------- Kernel 1: gates = sigmoid([Lx | L@state] @ Wg^T + bg) -----
// 8 waves/block, one wave per (b,m) row. W in LDS as float4 blocks with
// XOR swizzle p = j ^ (o&15) so stride-256B rows read conflict-free.
__global__ __launch_bounds__(512) void k_gates(
    const float* __restrict__ state, const float* __restrict__ LxT,
    const float* __restrict__ ell_val, const int* __restrict__ ell_col,
    const int* __restrict__ ell_cnt, const float* __restrict__ Wg,
    const float* __restrict__ bg, float* __restrict__ gates, int t) {
  __shared__ float4 sWv4[128][16];
  __shared__ float sWx[128];
  __shared__ float sb[128];
  __shared__ float sdiff[8][64];
  for (int idx = threadIdx.x; idx < 128 * 16; idx += 512) {
    int o = idx >> 4, p = idx & 15;
    int j = p ^ (o & 15);
    const float* src = Wg + o * 65 + 1 + j * 4;
    sWv4[o][p] = make_float4(src[0], src[1], src[2], src[3]);
  }
  if (threadIdx.x < 128) {
    sWx[threadIdx.x] = Wg[threadIdx.x * 65];
    sb[threadIdx.x]  = bg[threadIdx.x];
  }
  __syncthreads();
  int wv = threadIdx.x >> 6, lane = threadIdx.x & 63;
  int row = blockIdx.x * 8 + wv;          // b*N + m
  int b = row >> 11, m = row & (N_NODES - 1);
  const float* st = state + (size_t)b * (N_NODES * HID);
  int cnt = ell_cnt[m];
  float acc = 0.f;
  for (int k = 0; k < cnt; ++k) {
    int col = ell_col[m * CAP + k];       // wave-uniform
    float v = ell_val[m * CAP + k];
    acc += v * st[col * HID + lane];      // coalesced 256B gather
  }
  sdiff[wv][lane] = acc;                  // wave-private row, no barrier needed
  float Lxv = LxT[(size_t)m * TB + t * BATCH + b];
  float* gout = gates + (size_t)b * (N_NODES * 128) + m * 128;
  #pragma unroll
  for (int rep = 0; rep < 2; ++rep) {
    int o = lane + rep * 64;
    float s = sb[o] + Lxv * sWx[o];
    int sw = o & 15;
    #pragma unroll
    for (int j = 0; j < 16; ++j) {
      float4 w = sWv4[o][j ^ sw];
      const float4 d = *(const float4*)&sdiff[wv][j * 4];   // broadcast
      s += d.x * w.x + d.y * w.y + d.z * w.z + d.w * w.w;
    }
    gout[o] = 1.f / (1.f + __expf(-s));
  }
}

// ---------------- Kernel 2: cand + GRU update ------------------------------
// Flat-split semantics: r[b,j] = gates[b][j], u[b,j] = gates[b][N*H + j].
__global__ __launch_bounds__(512) void k_cand(
    const float* __restrict__ state, const float* __restrict__ LxT,
    const float* __restrict__ ell_val, const int* __restrict__ ell_col,
    const int* __restrict__ ell_cnt, const float* __restrict__ Wc,
    const float* __restrict__ bc, const float* __restrict__ gates,
    float* __restrict__ state_next, float* __restrict__ out, int t) {
  __shared__ float4 sWv4[64][16];
  __shared__ float sWx[64];
  __shared__ float sb[64];
  __shared__ float sdiff[8][64];
  for (int idx = threadIdx.x; idx < 64 * 16; idx += 512) {
    int o = idx >> 4, p = idx & 15;
    int j = p ^ (o & 15);
    const float* src = Wc + o * 65 + 1 + j * 4;
    sWv4[o][p] = make_float4(src[0], src[1], src[2], src[3]);
  }
  if (threadIdx.x < 64) {
    sWx[threadIdx.x] = Wc[threadIdx.x * 65];
    sb[threadIdx.x]  = bc[threadIdx.x];
  }
  __syncthreads();
  int wv = threadIdx.x >> 6, lane = threadIdx.x & 63;
  int row = blockIdx.x * 8 + wv;
  int b = row >> 11, m = row & (N_NODES - 1);
  const float* st = state + (size_t)b * (N_NODES * HID);
  const float* gb = gates + (size_t)b * (N_NODES * 128);
  int cnt = ell_cnt[m];
  float acc = 0.f;
  for (int k = 0; k < cnt; ++k) {
    int col = ell_col[m * CAP + k];
    float v = ell_val[m * CAP + k];
    int j = col * HID + lane;
    acc += v * (gb[j] * st[j]);           // rs = r * state, flat index
  }
  sdiff[wv][lane] = acc;
  float Lxv = LxT[(size_t)m * TB + t * BATCH + b];
  int o = lane;
  float s = sb[o] + Lxv * sWx[o];
  int sw = o & 15;
  #pragma unroll
  for (int j = 0; j < 16; ++j) {
    float4 w = sWv4[o][j ^ sw];
    const float4 d = *(const float4*)&sdiff[wv][j * 4];
    s += d.x * w.x + d.y * w.y + d.z * w.z + d.w * w.w;
  }
  float cand = tanhf(s);
  int jj = m * HID + o;
  float u = gb[N_NODES * HID + jj];
  float hp = st[jj];
  float nh = u * hp + (1.f - u) * cand;
  state_next[(size_t)b * (N_NODES * HID) + jj] = nh;
  out[((size_t)t * BATCH + b) * (N_NODES * HID) + jj] = nh;
}

extern "C" void kernel_launch(void* const* d_in, const int* in_sizes, int n_in,
                              void* d_out, int out_size, void* d_ws, size_t ws_size,
                              hipStream_t stream) {
  const float* x  = (const float*)d_in[0];
  const float* L  = (const float*)d_in[1];
  const float* Wg = (const float*)d_in[2];
  const float* bg = (const float*)d_in[3];
  const float* Wc = (const float*)d_in[4];
  const float* bc = (const float*)d_in[5];
  float* out = (float*)d_out;
  float* ws = (float*)d_ws;

  float* ell_val = ws;                                  // 2048*128
  int*   ell_col = (int*)(ws + (size_t)N_NODES * CAP);  // 2048*128
  int*   ell_cnt = (int*)(ws + (size_t)2 * N_NODES * CAP);  // 2048
  float* xT    = ws + (size_t)2 * N_NODES * CAP + N_NODES;  // 2048*256
  float* LxT   = xT + (size_t)N_NODES * TB;                 // 2048*256
  float* gates = LxT + (size_t)N_NODES * TB;                // 8*2048*128
  float* stA   = gates + (size_t)BATCH * N_NODES * 128;     // 8*2048*64
  float* stB   = stA + (size_t)BATCH * N_NODES * HID;

  k_build_ell<<<N_NODES / 4, 256, 0, stream>>>(L, ell_val, ell_col, ell_cnt);
  k_xt<<<256, 256, 0, stream>>>(x, xT);
  k_spmm_x<<<N_NODES / 8, 512, 0, stream>>>(xT, ell_val, ell_col, ell_cnt, LxT);
  hipMemsetAsync(stA, 0, (size_t)BATCH * N_NODES * HID * sizeof(float), stream);

  float* cur = stA;
  float* nxt = stB;
  for (int t = 0; t < SEQ; ++t) {
    k_gates<<<BATCH * N_NODES / 8, 512, 0, stream>>>(cur, LxT, ell_val, ell_col,
                                                     ell_cnt, Wg, bg, gates, t);
    k_cand<<<BATCH * N_NODES / 8, 512, 0, stream>>>(cur, LxT, ell_val, ell_col,
                                                    ell_cnt, Wc, bc, gates, nxt,
                                                    out, t);
    float* tmp = cur; cur = nxt; nxt = tmp;
  }
}

// Round 3
// 1280.081 us; speedup vs baseline: 3.3955x; 2.9432x over previous
//
#include <hip/hip_runtime.h>
#include <math.h>

#define N_NODES 2048
#define HID 64
#define BATCH 8
#define SEQ 32
#define CAP 128          // ELL slots per row (nnz/row ~33, padded to x8)
#define TB 256           // SEQ*BATCH
#define NH (N_NODES*HID) // 131072 per batch

__device__ __forceinline__ float fast_sig(float s) {
  return 1.f / (1.f + __expf(-s));
}
__device__ __forceinline__ float fast_tanh(float s) {
  float e = __expf(-2.f * fabsf(s));
  float t = 1.f - 2.f * e / (1.f + e);
  return copysignf(t, s);
}

// ---------------- Kernel 0: build padded ELL (colh = col*HID) ---------------
__global__ __launch_bounds__(256) void k_build_ell(
    const float* __restrict__ L, float* __restrict__ ell_val,
    int* __restrict__ ell_colh, int* __restrict__ ell_cnt) {
  int wave = (blockIdx.x * blockDim.x + threadIdx.x) >> 6;
  int lane = threadIdx.x & 63;
  if (wave >= N_NODES) return;
  const float* row = L + (size_t)wave * N_NODES;
  int base = 0;
  for (int c = 0; c < N_NODES / 64; ++c) {
    int col = c * 64 + lane;
    float v = row[col];
    bool nz = (v != 0.0f);
    unsigned long long mask = __ballot(nz);
    int before = __popcll(mask & ((1ull << lane) - 1ull));
    if (nz) {
      int slot = base + before;
      if (slot < CAP) {
        ell_colh[wave * CAP + slot] = col * HID;
        ell_val[wave * CAP + slot] = v;
      }
    }
    base += __popcll(mask);
  }
  if (base > CAP) base = CAP;
  int pad = (base + 7) & ~7;
  if (pad > CAP) pad = CAP;
  for (int s = base + lane; s < pad; s += 64) {
    ell_colh[wave * CAP + s] = 0;
    ell_val[wave * CAP + s] = 0.f;
  }
  if (lane == 0) ell_cnt[wave] = pad;
}

// ---------------- Transpose x[b][t][n] -> xT[n][tb],  tb = t*8 + b ----------
__global__ __launch_bounds__(256) void k_xt(const float* __restrict__ x,
                                            float* __restrict__ xT) {
  __shared__ float s[32][65];
  int n0  = (blockIdx.x & 63) * 32;
  int tb0 = (blockIdx.x >> 6) * 64;
  for (int idx = threadIdx.x; idx < 32 * 64; idx += 256) {
    int ln = idx & 31, ltb = idx >> 5;
    int tb = tb0 + ltb; int b = tb & 7, t = tb >> 3;
    s[ln][ltb] = x[((size_t)b * SEQ + t) * N_NODES + n0 + ln];
  }
  __syncthreads();
  for (int idx = threadIdx.x; idx < 32 * 64; idx += 256) {
    int ln = idx >> 6, ltb = idx & 63;
    xT[(size_t)(n0 + ln) * TB + tb0 + ltb] = s[ln][ltb];
  }
}

// ---------------- LxT[m][tb] = sum_n L[m,n] * xT[n][tb] ---------------------
__global__ __launch_bounds__(512) void k_spmm_x(
    const float* __restrict__ xT, const float* __restrict__ ell_val,
    const int* __restrict__ ell_colh, const int* __restrict__ ell_cnt,
    float* __restrict__ LxT) {
  int m = (blockIdx.x * blockDim.x + threadIdx.x) >> 6;
  int lane = threadIdx.x & 63;
  if (m >= N_NODES) return;
  const int* cp = ell_colh + m * CAP;
  const float* vp = ell_val + m * CAP;
  int cnt = ell_cnt[m];
  float4 acc = {0.f, 0.f, 0.f, 0.f};
  for (int k = 0; k < cnt; k += 4) {
    int4 c = *(const int4*)(cp + k);
    float4 v = *(const float4*)(vp + k);
    float4 xa = *(const float4*)&xT[(size_t)c.x * 4 + lane * 4];
    float4 xb = *(const float4*)&xT[(size_t)c.y * 4 + lane * 4];
    float4 xc = *(const float4*)&xT[(size_t)c.z * 4 + lane * 4];
    float4 xd = *(const float4*)&xT[(size_t)c.w * 4 + lane * 4];
    acc.x = fmaf(v.x, xa.x, acc.x); acc.y = fmaf(v.x, xa.y, acc.y);
    acc.z = fmaf(v.x, xa.z, acc.z); acc.w = fmaf(v.x, xa.w, acc.w);
    acc.x = fmaf(v.y, xb.x, acc.x); acc.y = fmaf(v.y, xb.y, acc.y);
    acc.z = fmaf(v.y, xb.z, acc.z); acc.w = fmaf(v.y, xb.w, acc.w);
    acc.x = fmaf(v.z, xc.x, acc.x); acc.y = fmaf(v.z, xc.y, acc.y);
    acc.z = fmaf(v.z, xc.z, acc.z); acc.w = fmaf(v.z, xc.w, acc.w);
    acc.x = fmaf(v.w, xd.x, acc.x); acc.y = fmaf(v.w, xd.y, acc.y);
    acc.z = fmaf(v.w, xd.z, acc.z); acc.w = fmaf(v.w, xd.w, acc.w);
  }
  *(float4*)&LxT[(size_t)m * TB + lane * 4] = acc;
}

// ---------------- Kernel 1: gates; writes rs = r*state (m<1024) or u --------
// One wave handles row m for 4 batches. Gather unrolled x8.
__global__ __launch_bounds__(512, 4) void k_gates(
    const float* __restrict__ state, const float* __restrict__ LxT,
    const float* __restrict__ ell_val, const int* __restrict__ ell_colh,
    const int* __restrict__ ell_cnt, const float* __restrict__ Wg,
    const float* __restrict__ bg, float* __restrict__ rsbuf,
    float* __restrict__ ubuf, int t) {
  __shared__ float4 sWv4[128][16];
  __shared__ float sWx[128];
  __shared__ float sb[128];
  __shared__ float sdiff[8][4][64];
  for (int idx = threadIdx.x; idx < 128 * 16; idx += 512) {
    int o = idx >> 4, p = idx & 15;
    int j = p ^ (o & 15);
    const float* src = Wg + o * 65 + 1 + j * 4;
    sWv4[o][p] = make_float4(src[0], src[1], src[2], src[3]);
  }
  if (threadIdx.x < 128) {
    sWx[threadIdx.x] = Wg[threadIdx.x * 65];
    sb[threadIdx.x]  = bg[threadIdx.x];
  }
  __syncthreads();
  int wv = threadIdx.x >> 6, lane = threadIdx.x & 63;
  int wid = blockIdx.x * 8 + wv;
  int m = wid >> 1, b0 = (wid & 1) * 4;
  const float* st0 = state + (size_t)(b0 + 0) * NH;
  const float* st1 = state + (size_t)(b0 + 1) * NH;
  const float* st2 = state + (size_t)(b0 + 2) * NH;
  const float* st3 = state + (size_t)(b0 + 3) * NH;
  const int* cp = ell_colh + m * CAP;
  const float* vp = ell_val + m * CAP;
  int cnt = ell_cnt[m];
  float a0 = 0.f, a1 = 0.f, a2 = 0.f, a3 = 0.f;
  for (int k = 0; k < cnt; k += 8) {
    int4 ca = *(const int4*)(cp + k);
    int4 cb = *(const int4*)(cp + k + 4);
    float4 va = *(const float4*)(vp + k);
    float4 vb = *(const float4*)(vp + k + 4);
#define GATH(C, V) { \
    float g0 = st0[C + lane], g1 = st1[C + lane]; \
    float g2 = st2[C + lane], g3 = st3[C + lane]; \
    a0 = fmaf(V, g0, a0); a1 = fmaf(V, g1, a1); \
    a2 = fmaf(V, g2, a2); a3 = fmaf(V, g3, a3); }
    GATH(ca.x, va.x) GATH(ca.y, va.y) GATH(ca.z, va.z) GATH(ca.w, va.w)
    GATH(cb.x, vb.x) GATH(cb.y, vb.y) GATH(cb.z, vb.z) GATH(cb.w, vb.w)
#undef GATH
  }
  sdiff[wv][0][lane] = a0;
  sdiff[wv][1][lane] = a1;
  sdiff[wv][2][lane] = a2;
  sdiff[wv][3][lane] = a3;
  float4 Lx4 = *(const float4*)&LxT[(size_t)m * TB + t * BATCH + b0];
  #pragma unroll
  for (int rep = 0; rep < 2; ++rep) {
    int o = lane + rep * 64;
    float bias = sb[o], wx = sWx[o];
    float s0 = fmaf(Lx4.x, wx, bias);
    float s1 = fmaf(Lx4.y, wx, bias);
    float s2 = fmaf(Lx4.z, wx, bias);
    float s3 = fmaf(Lx4.w, wx, bias);
    int sw = o & 15;
    #pragma unroll
    for (int j = 0; j < 16; ++j) {
      float4 w = sWv4[o][j ^ sw];
      float4 d0 = *(const float4*)&sdiff[wv][0][j * 4];
      float4 d1 = *(const float4*)&sdiff[wv][1][j * 4];
      float4 d2 = *(const float4*)&sdiff[wv][2][j * 4];
      float4 d3 = *(const float4*)&sdiff[wv][3][j * 4];
      s0 += d0.x*w.x + d0.y*w.y + d0.z*w.z + d0.w*w.w;
      s1 += d1.x*w.x + d1.y*w.y + d1.z*w.z + d1.w*w.w;
      s2 += d2.x*w.x + d2.y*w.y + d2.z*w.z + d2.w*w.w;
      s3 += d3.x*w.x + d3.y*w.y + d3.z*w.z + d3.w*w.w;
    }
    float g0 = fast_sig(s0), g1 = fast_sig(s1);
    float g2 = fast_sig(s2), g3 = fast_sig(s3);
    int i = m * 128 + rep * 64 + lane;   // flat index within half
    if (m < N_NODES / 2) {
      // r-half: flat gate idx == flat state idx; store r*state directly
      rsbuf[(size_t)(b0 + 0) * NH + i] = g0 * st0[i];
      rsbuf[(size_t)(b0 + 1) * NH + i] = g1 * st1[i];
      rsbuf[(size_t)(b0 + 2) * NH + i] = g2 * st2[i];
      rsbuf[(size_t)(b0 + 3) * NH + i] = g3 * st3[i];
    } else {
      int i2 = (m - N_NODES / 2) * 128 + rep * 64 + lane;
      ubuf[(size_t)(b0 + 0) * NH + i2] = g0;
      ubuf[(size_t)(b0 + 1) * NH + i2] = g1;
      ubuf[(size_t)(b0 + 2) * NH + i2] = g2;
      ubuf[(size_t)(b0 + 3) * NH + i2] = g3;
    }
  }
}

// ---------------- Kernel 2: cand + GRU update (gathers rsbuf) ---------------
__global__ __launch_bounds__(512, 4) void k_cand(
    const float* __restrict__ state, const float* __restrict__ LxT,
    const float* __restrict__ ell_val, const int* __restrict__ ell_colh,
    const int* __restrict__ ell_cnt, const float* __restrict__ Wc,
    const float* __restrict__ bc, const float* __restrict__ rsbuf,
    const float* __restrict__ ubuf, float* __restrict__ state_next,
    float* __restrict__ out, int t) {
  __shared__ float4 sWv4[64][16];
  __shared__ float sWx[64];
  __shared__ float sb[64];
  __shared__ float sdiff[8][4][64];
  for (int idx = threadIdx.x; idx < 64 * 16; idx += 512) {
    int o = idx >> 4, p = idx & 15;
    int j = p ^ (o & 15);
    const float* src = Wc + o * 65 + 1 + j * 4;
    sWv4[o][p] = make_float4(src[0], src[1], src[2], src[3]);
  }
  if (threadIdx.x < 64) {
    sWx[threadIdx.x] = Wc[threadIdx.x * 65];
    sb[threadIdx.x]  = bc[threadIdx.x];
  }
  __syncthreads();
  int wv = threadIdx.x >> 6, lane = threadIdx.x & 63;
  int wid = blockIdx.x * 8 + wv;
  int m = wid >> 1, b0 = (wid & 1) * 4;
  const float* rs0 = rsbuf + (size_t)(b0 + 0) * NH;
  const float* rs1 = rsbuf + (size_t)(b0 + 1) * NH;
  const float* rs2 = rsbuf + (size_t)(b0 + 2) * NH;
  const float* rs3 = rsbuf + (size_t)(b0 + 3) * NH;
  const int* cp = ell_colh + m * CAP;
  const float* vp = ell_val + m * CAP;
  int cnt = ell_cnt[m];
  float a0 = 0.f, a1 = 0.f, a2 = 0.f, a3 = 0.f;
  for (int k = 0; k < cnt; k += 8) {
    int4 ca = *(const int4*)(cp + k);
    int4 cb = *(const int4*)(cp + k + 4);
    float4 va = *(const float4*)(vp + k);
    float4 vb = *(const float4*)(vp + k + 4);
#define GATH(C, V) { \
    float g0 = rs0[C + lane], g1 = rs1[C + lane]; \
    float g2 = rs2[C + lane], g3 = rs3[C + lane]; \
    a0 = fmaf(V, g0, a0); a1 = fmaf(V, g1, a1); \
    a2 = fmaf(V, g2, a2); a3 = fmaf(V, g3, a3); }
    GATH(ca.x, va.x) GATH(ca.y, va.y) GATH(ca.z, va.z) GATH(ca.w, va.w)
    GATH(cb.x, vb.x) GATH(cb.y, vb.y) GATH(cb.z, vb.z) GATH(cb.w, vb.w)
#undef GATH
  }
  sdiff[wv][0][lane] = a0;
  sdiff[wv][1][lane] = a1;
  sdiff[wv][2][lane] = a2;
  sdiff[wv][3][lane] = a3;
  float4 Lx4 = *(const float4*)&LxT[(size_t)m * TB + t * BATCH + b0];
  int o = lane;
  float bias = sb[o], wx = sWx[o];
  float s0 = fmaf(Lx4.x, wx, bias);
  float s1 = fmaf(Lx4.y, wx, bias);
  float s2 = fmaf(Lx4.z, wx, bias);
  float s3 = fmaf(Lx4.w, wx, bias);
  int sw = o & 15;
  #pragma unroll
  for (int j = 0; j < 16; ++j) {
    float4 w = sWv4[o][j ^ sw];
    float4 d0 = *(const float4*)&sdiff[wv][0][j * 4];
    float4 d1 = *(const float4*)&sdiff[wv][1][j * 4];
    float4 d2 = *(const float4*)&sdiff[wv][2][j * 4];
    float4 d3 = *(const float4*)&sdiff[wv][3][j * 4];
    s0 += d0.x*w.x + d0.y*w.y + d0.z*w.z + d0.w*w.w;
    s1 += d1.x*w.x + d1.y*w.y + d1.z*w.z + d1.w*w.w;
    s2 += d2.x*w.x + d2.y*w.y + d2.z*w.z + d2.w*w.w;
    s3 += d3.x*w.x + d3.y*w.y + d3.z*w.z + d3.w*w.w;
  }
  int jj = m * HID + lane;
  const float* st = state + jj;
  const float* ub = ubuf + jj;
  float* nx = state_next + jj;
  float* op = out + ((size_t)t * BATCH) * NH + jj;
  float c0 = fast_tanh(s0), c1 = fast_tanh(s1);
  float c2 = fast_tanh(s2), c3 = fast_tanh(s3);
#define UPD(i, c) { \
    float u = ub[(size_t)(b0 + i) * NH]; \
    float hp = st[(size_t)(b0 + i) * NH]; \
    float nh = u * hp + (1.f - u) * c; \
    nx[(size_t)(b0 + i) * NH] = nh; \
    op[(size_t)(b0 + i) * NH] = nh; }
  UPD(0, c0) UPD(1, c1) UPD(2, c2) UPD(3, c3)
#undef UPD
}

extern "C" void kernel_launch(void* const* d_in, const int* in_sizes, int n_in,
                              void* d_out, int out_size, void* d_ws, size_t ws_size,
                              hipStream_t stream) {
  const float* x  = (const float*)d_in[0];
  const float* L  = (const float*)d_in[1];
  const float* Wg = (const float*)d_in[2];
  const float* bg = (const float*)d_in[3];
  const float* Wc = (const float*)d_in[4];
  const float* bc = (const float*)d_in[5];
  float* out = (float*)d_out;
  float* ws = (float*)d_ws;

  float* ell_val  = ws;                                     // N*CAP
  int*   ell_colh = (int*)(ws + (size_t)N_NODES * CAP);     // N*CAP
  int*   ell_cnt  = (int*)(ws + (size_t)2 * N_NODES * CAP); // N
  float* xT    = ws + (size_t)2 * N_NODES * CAP + N_NODES;  // N*TB
  float* LxT   = xT + (size_t)N_NODES * TB;                 // N*TB
  float* rsbuf = LxT + (size_t)N_NODES * TB;                // B*NH
  float* ubuf  = rsbuf + (size_t)BATCH * NH;                // B*NH
  float* stA   = ubuf + (size_t)BATCH * NH;                 // B*NH
  float* stB   = stA + (size_t)BATCH * NH;                  // B*NH

  k_build_ell<<<N_NODES / 4, 256, 0, stream>>>(L, ell_val, ell_colh, ell_cnt);
  k_xt<<<256, 256, 0, stream>>>(x, xT);
  k_spmm_x<<<N_NODES / 8, 512, 0, stream>>>(xT, ell_val, ell_colh, ell_cnt, LxT);
  hipMemsetAsync(stA, 0, (size_t)BATCH * NH * sizeof(float), stream);

  float* cur = stA;
  float* nxt = stB;
  for (int t = 0; t < SEQ; ++t) {
    k_gates<<<512, 512, 0, stream>>>(cur, LxT, ell_val, ell_colh, ell_cnt,
                                     Wg, bg, rsbuf, ubuf, t);
    k_cand<<<512, 512, 0, stream>>>(cur, LxT, ell_val, ell_colh, ell_cnt,
                                    Wc, bc, rsbuf, ubuf, nxt, out, t);
    float* tmp = cur; cur = nxt; nxt = tmp;
  }
}

// Round 4
// 1209.666 us; speedup vs baseline: 3.5931x; 1.0582x over previous
//
#include <hip/hip_runtime.h>
#include <math.h>

#define N_NODES 2048
#define HID 64
#define BATCH 8
#define SEQ 32
#define CAP 128          // ELL slots per row (nnz/row ~33, padded to x8)
#define TB 256           // SEQ*BATCH
#define NH (N_NODES*HID) // 131072 per batch

__device__ __forceinline__ float fast_sig(float s) {
  return 1.f / (1.f + __expf(-s));
}
__device__ __forceinline__ float fast_tanh(float s) {
  float e = __expf(-2.f * fabsf(s));
  float t = 1.f - 2.f * e / (1.f + e);
  return copysignf(t, s);
}

// ---------------- Kernel 0: build padded ELL (colh = col*HID) ---------------
__global__ __launch_bounds__(256) void k_build_ell(
    const float* __restrict__ L, float* __restrict__ ell_val,
    int* __restrict__ ell_colh, int* __restrict__ ell_cnt) {
  int wave = (blockIdx.x * blockDim.x + threadIdx.x) >> 6;
  int lane = threadIdx.x & 63;
  if (wave >= N_NODES) return;
  const float* row = L + (size_t)wave * N_NODES;
  int base = 0;
  for (int c = 0; c < N_NODES / 64; ++c) {
    int col = c * 64 + lane;
    float v = row[col];
    bool nz = (v != 0.0f);
    unsigned long long mask = __ballot(nz);
    int before = __popcll(mask & ((1ull << lane) - 1ull));
    if (nz) {
      int slot = base + before;
      if (slot < CAP) {
        ell_colh[wave * CAP + slot] = col * HID;
        ell_val[wave * CAP + slot] = v;
      }
    }
    base += __popcll(mask);
  }
  if (base > CAP) base = CAP;
  int pad = (base + 7) & ~7;
  if (pad > CAP) pad = CAP;
  for (int s = base + lane; s < pad; s += 64) {
    ell_colh[wave * CAP + s] = 0;
    ell_val[wave * CAP + s] = 0.f;
  }
  if (lane == 0) ell_cnt[wave] = pad;
}

// ---------------- Transpose x[b][t][n] -> xT[n][tb],  tb = t*8 + b ----------
__global__ __launch_bounds__(256) void k_xt(const float* __restrict__ x,
                                            float* __restrict__ xT) {
  __shared__ float s[32][65];
  int n0  = (blockIdx.x & 63) * 32;
  int tb0 = (blockIdx.x >> 6) * 64;
  for (int idx = threadIdx.x; idx < 32 * 64; idx += 256) {
    int ln = idx & 31, ltb = idx >> 5;
    int tb = tb0 + ltb; int b = tb & 7, t = tb >> 3;
    s[ln][ltb] = x[((size_t)b * SEQ + t) * N_NODES + n0 + ln];
  }
  __syncthreads();
  for (int idx = threadIdx.x; idx < 32 * 64; idx += 256) {
    int ln = idx >> 6, ltb = idx & 63;
    xT[(size_t)(n0 + ln) * TB + tb0 + ltb] = s[ln][ltb];
  }
}

// ---------------- LxT[m][tb] = sum_n L[m,n] * xT[n][tb] ---------------------
__global__ __launch_bounds__(512) void k_spmm_x(
    const float* __restrict__ xT, const float* __restrict__ ell_val,
    const int* __restrict__ ell_colh, const int* __restrict__ ell_cnt,
    float* __restrict__ LxT) {
  int m = (blockIdx.x * blockDim.x + threadIdx.x) >> 6;
  int lane = threadIdx.x & 63;
  if (m >= N_NODES) return;
  const int* cp = ell_colh + m * CAP;
  const float* vp = ell_val + m * CAP;
  int cnt = ell_cnt[m];
  float4 acc = {0.f, 0.f, 0.f, 0.f};
  for (int k = 0; k < cnt; k += 4) {
    int4 c = *(const int4*)(cp + k);
    float4 v = *(const float4*)(vp + k);
    float4 xa = *(const float4*)&xT[(size_t)c.x * 4 + lane * 4];
    float4 xb = *(const float4*)&xT[(size_t)c.y * 4 + lane * 4];
    float4 xc = *(const float4*)&xT[(size_t)c.z * 4 + lane * 4];
    float4 xd = *(const float4*)&xT[(size_t)c.w * 4 + lane * 4];
    acc.x = fmaf(v.x, xa.x, acc.x); acc.y = fmaf(v.x, xa.y, acc.y);
    acc.z = fmaf(v.x, xa.z, acc.z); acc.w = fmaf(v.x, xa.w, acc.w);
    acc.x = fmaf(v.y, xb.x, acc.x); acc.y = fmaf(v.y, xb.y, acc.y);
    acc.z = fmaf(v.y, xb.z, acc.z); acc.w = fmaf(v.y, xb.w, acc.w);
    acc.x = fmaf(v.z, xc.x, acc.x); acc.y = fmaf(v.z, xc.y, acc.y);
    acc.z = fmaf(v.z, xc.z, acc.z); acc.w = fmaf(v.z, xc.w, acc.w);
    acc.x = fmaf(v.w, xd.x, acc.x); acc.y = fmaf(v.w, xd.y, acc.y);
    acc.z = fmaf(v.w, xd.z, acc.z); acc.w = fmaf(v.w, xd.w, acc.w);
  }
  *(float4*)&LxT[(size_t)m * TB + lane * 4] = acc;
}

// ---------------- Kernel 1: gates; one wave = one row m, ALL 8 batches ------
// Packed gather: lane (g=lane>>4, sub=lane&15) loads float4 of state
// [batch g][col*64 + sub*4] (load A) and [batch g+4][...] (load B):
// 2 dwordx4 per nnz cover all 8 batches x 64 h.
__global__ __launch_bounds__(256, 4) void k_gates(
    const float* __restrict__ state, const float* __restrict__ LxT,
    const float* __restrict__ ell_val, const int* __restrict__ ell_colh,
    const int* __restrict__ ell_cnt, const float* __restrict__ Wg,
    const float* __restrict__ bg, float* __restrict__ rsbuf,
    float* __restrict__ ubuf, int t) {
  __shared__ float4 sWv4[128][16];
  __shared__ float sWx[128];
  __shared__ float sb[128];
  __shared__ float4 sdiff4[4][8][16];
  for (int idx = threadIdx.x; idx < 128 * 16; idx += 256) {
    int o = idx >> 4, p = idx & 15;
    int j = p ^ (o & 15);
    const float* src = Wg + o * 65 + 1 + j * 4;
    sWv4[o][p] = make_float4(src[0], src[1], src[2], src[3]);
  }
  if (threadIdx.x < 128) {
    sWx[threadIdx.x] = Wg[threadIdx.x * 65];
    sb[threadIdx.x]  = bg[threadIdx.x];
  }
  __syncthreads();
  int wv = threadIdx.x >> 6, lane = threadIdx.x & 63;
  int m = blockIdx.x * 4 + wv;
  int g = lane >> 4, sub4 = (lane & 15) << 2;
  const float* pA = state + (size_t)g * NH + sub4;
  const float* pB = pA + (size_t)4 * NH;
  const int* cp = ell_colh + m * CAP;
  const float* vp = ell_val + m * CAP;
  int cnt = ell_cnt[m];
  float4 aA = {0.f, 0.f, 0.f, 0.f};
  float4 aB = {0.f, 0.f, 0.f, 0.f};
  for (int k = 0; k < cnt; k += 8) {
    int4 ca = *(const int4*)(cp + k);
    int4 cb = *(const int4*)(cp + k + 4);
    float4 va = *(const float4*)(vp + k);
    float4 vb = *(const float4*)(vp + k + 4);
#define GATH(C, V) { \
    float4 sA = *(const float4*)(pA + C); \
    float4 sB = *(const float4*)(pB + C); \
    aA.x = fmaf(V, sA.x, aA.x); aA.y = fmaf(V, sA.y, aA.y); \
    aA.z = fmaf(V, sA.z, aA.z); aA.w = fmaf(V, sA.w, aA.w); \
    aB.x = fmaf(V, sB.x, aB.x); aB.y = fmaf(V, sB.y, aB.y); \
    aB.z = fmaf(V, sB.z, aB.z); aB.w = fmaf(V, sB.w, aB.w); }
    GATH(ca.x, va.x) GATH(ca.y, va.y) GATH(ca.z, va.z) GATH(ca.w, va.w)
    GATH(cb.x, vb.x) GATH(cb.y, vb.y) GATH(cb.z, vb.z) GATH(cb.w, vb.w)
#undef GATH
  }
  sdiff4[wv][g][lane & 15] = aA;       // b = g,   h = sub4..sub4+3
  sdiff4[wv][g + 4][lane & 15] = aB;   // b = g+4  (wave-private, no barrier)
  float4 LxLo = *(const float4*)&LxT[(size_t)m * TB + t * BATCH];
  float4 LxHi = *(const float4*)&LxT[(size_t)m * TB + t * BATCH + 4];
  float Lx8[8] = {LxLo.x, LxLo.y, LxLo.z, LxLo.w, LxHi.x, LxHi.y, LxHi.z, LxHi.w};
  int o0 = lane, o1 = lane + 64;
  int sw0 = o0 & 15, sw1 = o1 & 15;
  float wx0 = sWx[o0], b0_ = sb[o0];
  float wx1 = sWx[o1], b1_ = sb[o1];
  float s0[8], s1[8];
  #pragma unroll
  for (int b = 0; b < 8; ++b) {
    s0[b] = fmaf(Lx8[b], wx0, b0_);
    s1[b] = fmaf(Lx8[b], wx1, b1_);
  }
  #pragma unroll
  for (int j = 0; j < 16; ++j) {
    float4 w0 = sWv4[o0][j ^ sw0];
    float4 w1 = sWv4[o1][j ^ sw1];
    #pragma unroll
    for (int b = 0; b < 8; ++b) {
      float4 d = sdiff4[wv][b][j];    // broadcast read
      s0[b] += d.x * w0.x + d.y * w0.y + d.z * w0.z + d.w * w0.w;
      s1[b] += d.x * w1.x + d.y * w1.y + d.z * w1.z + d.w * w1.w;
    }
  }
  if (m < N_NODES / 2) {
    // r-half: flat gate idx == flat state idx; store r*state directly
    int i0 = m * 128 + o0, i1 = m * 128 + o1;
    #pragma unroll
    for (int b = 0; b < 8; ++b) {
      const float* st = state + (size_t)b * NH;
      rsbuf[(size_t)b * NH + i0] = fast_sig(s0[b]) * st[i0];
      rsbuf[(size_t)b * NH + i1] = fast_sig(s1[b]) * st[i1];
    }
  } else {
    int i0 = (m - N_NODES / 2) * 128 + o0, i1 = (m - N_NODES / 2) * 128 + o1;
    #pragma unroll
    for (int b = 0; b < 8; ++b) {
      ubuf[(size_t)b * NH + i0] = fast_sig(s0[b]);
      ubuf[(size_t)b * NH + i1] = fast_sig(s1[b]);
    }
  }
}

// ---------------- Kernel 2: cand + GRU update (gathers rsbuf, packed) -------
__global__ __launch_bounds__(256, 4) void k_cand(
    const float* __restrict__ state, const float* __restrict__ LxT,
    const float* __restrict__ ell_val, const int* __restrict__ ell_colh,
    const int* __restrict__ ell_cnt, const float* __restrict__ Wc,
    const float* __restrict__ bc, const float* __restrict__ rsbuf,
    const float* __restrict__ ubuf, float* __restrict__ state_next,
    float* __restrict__ out, int t) {
  __shared__ float4 sWv4[64][16];
  __shared__ float sWx[64];
  __shared__ float sb[64];
  __shared__ float4 sdiff4[4][8][16];
  for (int idx = threadIdx.x; idx < 64 * 16; idx += 256) {
    int o = idx >> 4, p = idx & 15;
    int j = p ^ (o & 15);
    const float* src = Wc + o * 65 + 1 + j * 4;
    sWv4[o][p] = make_float4(src[0], src[1], src[2], src[3]);
  }
  if (threadIdx.x < 64) {
    sWx[threadIdx.x] = Wc[threadIdx.x * 65];
    sb[threadIdx.x]  = bc[threadIdx.x];
  }
  __syncthreads();
  int wv = threadIdx.x >> 6, lane = threadIdx.x & 63;
  int m = blockIdx.x * 4 + wv;
  int g = lane >> 4, sub4 = (lane & 15) << 2;
  const float* pA = rsbuf + (size_t)g * NH + sub4;
  const float* pB = pA + (size_t)4 * NH;
  const int* cp = ell_colh + m * CAP;
  const float* vp = ell_val + m * CAP;
  int cnt = ell_cnt[m];
  float4 aA = {0.f, 0.f, 0.f, 0.f};
  float4 aB = {0.f, 0.f, 0.f, 0.f};
  for (int k = 0; k < cnt; k += 8) {
    int4 ca = *(const int4*)(cp + k);
    int4 cb = *(const int4*)(cp + k + 4);
    float4 va = *(const float4*)(vp + k);
    float4 vb = *(const float4*)(vp + k + 4);
#define GATH(C, V) { \
    float4 sA = *(const float4*)(pA + C); \
    float4 sB = *(const float4*)(pB + C); \
    aA.x = fmaf(V, sA.x, aA.x); aA.y = fmaf(V, sA.y, aA.y); \
    aA.z = fmaf(V, sA.z, aA.z); aA.w = fmaf(V, sA.w, aA.w); \
    aB.x = fmaf(V, sB.x, aB.x); aB.y = fmaf(V, sB.y, aB.y); \
    aB.z = fmaf(V, sB.z, aB.z); aB.w = fmaf(V, sB.w, aB.w); }
    GATH(ca.x, va.x) GATH(ca.y, va.y) GATH(ca.z, va.z) GATH(ca.w, va.w)
    GATH(cb.x, vb.x) GATH(cb.y, vb.y) GATH(cb.z, vb.z) GATH(cb.w, vb.w)
#undef GATH
  }
  sdiff4[wv][g][lane & 15] = aA;
  sdiff4[wv][g + 4][lane & 15] = aB;
  float4 LxLo = *(const float4*)&LxT[(size_t)m * TB + t * BATCH];
  float4 LxHi = *(const float4*)&LxT[(size_t)m * TB + t * BATCH + 4];
  float Lx8[8] = {LxLo.x, LxLo.y, LxLo.z, LxLo.w, LxHi.x, LxHi.y, LxHi.z, LxHi.w};
  int o = lane, sw = o & 15;
  float wx = sWx[o], bias = sb[o];
  float s[8];
  #pragma unroll
  for (int b = 0; b < 8; ++b) s[b] = fmaf(Lx8[b], wx, bias);
  #pragma unroll
  for (int j = 0; j < 16; ++j) {
    float4 w = sWv4[o][j ^ sw];
    #pragma unroll
    for (int b = 0; b < 8; ++b) {
      float4 d = sdiff4[wv][b][j];    // broadcast read
      s[b] += d.x * w.x + d.y * w.y + d.z * w.z + d.w * w.w;
    }
  }
  int jj = m * HID + o;
  #pragma unroll
  for (int b = 0; b < 8; ++b) {
    float u = ubuf[(size_t)b * NH + jj];
    float hp = state[(size_t)b * NH + jj];
    float nh = u * hp + (1.f - u) * fast_tanh(s[b]);
    state_next[(size_t)b * NH + jj] = nh;
    out[((size_t)t * BATCH + b) * NH + jj] = nh;
  }
}

extern "C" void kernel_launch(void* const* d_in, const int* in_sizes, int n_in,
                              void* d_out, int out_size, void* d_ws, size_t ws_size,
                              hipStream_t stream) {
  const float* x  = (const float*)d_in[0];
  const float* L  = (const float*)d_in[1];
  const float* Wg = (const float*)d_in[2];
  const float* bg = (const float*)d_in[3];
  const float* Wc = (const float*)d_in[4];
  const float* bc = (const float*)d_in[5];
  float* out = (float*)d_out;
  float* ws = (float*)d_ws;

  float* ell_val  = ws;                                     // N*CAP
  int*   ell_colh = (int*)(ws + (size_t)N_NODES * CAP);     // N*CAP
  int*   ell_cnt  = (int*)(ws + (size_t)2 * N_NODES * CAP); // N
  float* xT    = ws + (size_t)2 * N_NODES * CAP + N_NODES;  // N*TB
  float* LxT   = xT + (size_t)N_NODES * TB;                 // N*TB
  float* rsbuf = LxT + (size_t)N_NODES * TB;                // B*NH
  float* ubuf  = rsbuf + (size_t)BATCH * NH;                // B*NH
  float* stA   = ubuf + (size_t)BATCH * NH;                 // B*NH
  float* stB   = stA + (size_t)BATCH * NH;                  // B*NH

  k_build_ell<<<N_NODES / 4, 256, 0, stream>>>(L, ell_val, ell_colh, ell_cnt);
  k_xt<<<256, 256, 0, stream>>>(x, xT);
  k_spmm_x<<<N_NODES / 8, 512, 0, stream>>>(xT, ell_val, ell_colh, ell_cnt, LxT);
  hipMemsetAsync(stA, 0, (size_t)BATCH * NH * sizeof(float), stream);

  float* cur = stA;
  float* nxt = stB;
  for (int t = 0; t < SEQ; ++t) {
    k_gates<<<N_NODES / 4, 256, 0, stream>>>(cur, LxT, ell_val, ell_colh,
                                             ell_cnt, Wg, bg, rsbuf, ubuf, t);
    k_cand<<<N_NODES / 4, 256, 0, stream>>>(cur, LxT, ell_val, ell_colh,
                                            ell_cnt, Wc, bc, rsbuf, ubuf, nxt,
                                            out, t);
    float* tmp = cur; cur = nxt; nxt = tmp;
  }
}